// Round 1
// baseline (57.569 us; speedup 1.0000x reference)
//
#include <hip/hip_runtime.h>

// EMA recurrence: y_0 = x_0; y_t = alpha*x_t + (1-alpha)*y_{t-1}
// x: [B=8, T=8192, F=512] fp32.
//
// Strategy: the recurrence is a contraction (decay c=0.9). 0.9^192 ~ 1.7e-9,
// so each T-chunk of 256 can be computed independently by warming up the
// carry from zero over a 192-step halo. This turns a 4096-way-parallel scan
// into a 131072-thread embarrassingly-parallel kernel at 1.75x read cost.

constexpr int   B_    = 8;
constexpr int   T_    = 8192;
constexpr int   F_    = 512;
constexpr int   CHUNK = 256;
constexpr int   HALO  = 192;
constexpr float ALPHA = 0.1f;
constexpr float DECAY = 0.9f;

__global__ __launch_bounds__(256, 4)
void ema_chunked_kernel(const float* __restrict__ x, float* __restrict__ y) {
    const int f     = blockIdx.x * 256 + threadIdx.x;   // 0..511
    const int chunk = blockIdx.y;                        // 0..31
    const int b     = blockIdx.z;                        // 0..7

    const int t0 = chunk * CHUNK;
    const size_t base = (size_t)b * T_ * F_ + f;

    float s = 0.0f;
    int tstart = t0;

    if (chunk == 0) {
        // exact start: y_0 = x_0
        s = x[base];
        y[base] = s;
        tstart = 1;
    } else {
        // halo warm-up: start carry from 0 at t0-HALO; error ~ 0.9^HALO ~ 2e-9
        const float* p = x + base + (size_t)(t0 - HALO) * F_;
        #pragma unroll 8
        for (int i = 0; i < HALO; ++i) {
            s = fmaf(DECAY, s, ALPHA * p[0]);
            p += F_;
        }
    }

    const float* p = x + base + (size_t)tstart * F_;
    float*       q = y + base + (size_t)tstart * F_;
    const int n = t0 + CHUNK - tstart;
    #pragma unroll 8
    for (int i = 0; i < n; ++i) {
        s = fmaf(DECAY, s, ALPHA * p[0]);
        q[0] = s;
        p += F_;
        q += F_;
    }
}

extern "C" void kernel_launch(void* const* d_in, const int* in_sizes, int n_in,
                              void* d_out, int out_size, void* d_ws, size_t ws_size,
                              hipStream_t stream) {
    const float* x = (const float*)d_in[0];
    float* y = (float*)d_out;

    dim3 grid(F_ / 256, T_ / CHUNK, B_);   // (2, 32, 8) = 512 blocks
    dim3 block(256);
    ema_chunked_kernel<<<grid, block, 0, stream>>>(x, y);
}